// Round 10
// baseline (462.273 us; speedup 1.0000x reference)
//
#include <hip/hip_runtime.h>

// TinyLlamaBlock on MI355X (gfx950). Inputs fp32, output fp32 (validated R5).
// Internal compute bf16 via v_mfma_f32_16x16x32_bf16, fp32 accumulate.
// R13: per-call GEMM pipeline selection. R12 evidence: counted-vmcnt dbuf
// (64KB LDS) helped tail GEMMs (512 blocks = 2/CU either way, -34us combined)
// but HURT the mega-GEMM (1536 blocks: 2.5 -> 2 blocks/CU residency loss,
// 99.4 -> 123.9us, MfmaUtil 46.5 -> 36). R13: gemm_bt<MODE, PIPE> — PIPE=0
// single-buffer BK=64 (R11 structure, 32KB LDS) for the mega-GEMM; PIPE=1
// R12 dbuf counted-vmcnt pipeline for the tails. Attn unchanged from R10.
//
// Workspace (67.11 MB):
//   [0, 50331648)        qkv bf16 [4096][6144]: cols [0,2048)=Q (later n2),
//                        [2048,4096)=K (later x1), [4096,6144)=V (later ctx)
//   [50331648, 67108864) R2 16.78 MB: WqT|WkT -> (after mega) WoT|WmlpT
// d_out (33.55 MB): lower n1 bf16 [4096][2048]; upper WvT bf16 [2048][2048]
// -> vT [32][128][2048] (after mega-GEMM); final GEMM rewrites all as fp32.

typedef unsigned short ushort_t;
typedef __attribute__((ext_vector_type(8))) short short8;
typedef __attribute__((ext_vector_type(4))) float floatx4;

__device__ __forceinline__ ushort_t f2bf(float f) {
  union { float f; unsigned u; } v; v.f = f;
  unsigned r = v.u + 0x7fffu + ((v.u >> 16) & 1u);  // RNE
  return (ushort_t)(r >> 16);
}
__device__ __forceinline__ float bf2f(unsigned h) {
  union { unsigned u; float f; } v; v.u = h << 16; return v.f;
}
// async 16B/lane global->LDS; LDS dest = wave-uniform base + lane*16
__device__ __forceinline__ void load16(const ushort_t* g, ushort_t* l) {
  __builtin_amdgcn_global_load_lds(
      (const __attribute__((address_space(1))) unsigned*)g,
      (__attribute__((address_space(3))) unsigned*)l, 16, 0, 0);
}

// ---------------------------------------------------------------------------
// Batched weight transpose+convert: fp32 [2048][2048] (k,n) -> bf16 (n,k).
// blockIdx.z selects which (src,dst) pair.
// ---------------------------------------------------------------------------
__global__ __launch_bounds__(256) void transpose_w_batch(
    const float* __restrict__ s0, const float* __restrict__ s1,
    const float* __restrict__ s2, ushort_t* __restrict__ d0,
    ushort_t* __restrict__ d1, ushort_t* __restrict__ d2) {
  __shared__ __align__(16) ushort_t tile[64][72];  // [n][k]
  const float* src = s0;
  ushort_t* dst = d0;
  if (blockIdx.z == 1) { src = s1; dst = d1; }
  else if (blockIdx.z == 2) { src = s2; dst = d2; }
  const int t = threadIdx.x;
  const int n0 = blockIdx.x * 64, k0 = blockIdx.y * 64;
#pragma unroll
  for (int i = 0; i < 4; ++i) {
    int c = t + 256 * i;            // 64 k-rows x 16 chunks of 4 floats
    int r = c >> 4, o = (c & 15) * 4;
    float4 raw = *(const float4*)&src[(size_t)(k0 + r) * 2048 + n0 + o];
    tile[o + 0][r] = f2bf(raw.x);
    tile[o + 1][r] = f2bf(raw.y);
    tile[o + 2][r] = f2bf(raw.z);
    tile[o + 3][r] = f2bf(raw.w);
  }
  __syncthreads();
#pragma unroll
  for (int i = 0; i < 2; ++i) {
    int c = t + 256 * i;            // 64 n-rows x 8 chunks of 8 bf16
    int r = c >> 3, o = (c & 7) * 8;
    *(uint4*)&dst[(size_t)(n0 + r) * 2048 + k0 + o] = *(const uint4*)&tile[r][o];
  }
}

// ---------------------------------------------------------------------------
// RMSNorm [4096][2048] -> bf16 (strided in/out). XBF: input bf16 else fp32.
// ---------------------------------------------------------------------------
template <bool XBF>
__global__ __launch_bounds__(256) void rmsnorm_kernel(
    const void* __restrict__ xv, int in_ld, const float* __restrict__ g,
    ushort_t* __restrict__ out, int out_ld) {
  const int row = blockIdx.x, t = threadIdx.x;
  float v[8];
  if (XBF) {
    uint4 raw = *(const uint4*)((const ushort_t*)xv + (size_t)row * in_ld + t * 8);
    v[0] = bf2f(raw.x & 0xffffu); v[1] = bf2f(raw.x >> 16);
    v[2] = bf2f(raw.y & 0xffffu); v[3] = bf2f(raw.y >> 16);
    v[4] = bf2f(raw.z & 0xffffu); v[5] = bf2f(raw.z >> 16);
    v[6] = bf2f(raw.w & 0xffffu); v[7] = bf2f(raw.w >> 16);
  } else {
    const float* xr = (const float*)xv + (size_t)row * in_ld + t * 8;
    float4 a = *(const float4*)xr;
    float4 b = *(const float4*)(xr + 4);
    v[0] = a.x; v[1] = a.y; v[2] = a.z; v[3] = a.w;
    v[4] = b.x; v[5] = b.y; v[6] = b.z; v[7] = b.w;
  }
  float ss = 0.f;
#pragma unroll
  for (int i = 0; i < 8; ++i) ss += v[i] * v[i];
#pragma unroll
  for (int m = 32; m >= 1; m >>= 1) ss += __shfl_xor(ss, m, 64);
  __shared__ float red[4];
  if ((t & 63) == 0) red[t >> 6] = ss;
  __syncthreads();
  float rs = rsqrtf((red[0] + red[1] + red[2] + red[3]) * (1.0f / 2048.0f) + 1e-5f);
  const float* gp = g + t * 8;
  float4 ga = *(const float4*)gp;
  float4 gb = *(const float4*)(gp + 4);
  float gv[8] = {ga.x, ga.y, ga.z, ga.w, gb.x, gb.y, gb.z, gb.w};
  union { ushort_t u16[8]; uint4 u; } p;
#pragma unroll
  for (int i = 0; i < 8; ++i) p.u16[i] = f2bf(v[i] * rs * gv[i]);
  *(uint4*)&out[(size_t)row * out_ld + t * 8] = p.u;
}

// ---------------------------------------------------------------------------
// GEMM: C[M,N] = A[M,K](bf16, lda) * Bt[N,K](bf16, ldb)^T.
// 128x128 tile, BK=64, XOR-swizzled LDS (linear gload_lds dest, pre-swizzled
// per-lane GLOBAL source, same-involution swizzled ds_read; conflicts=0).
// PIPE=0: single-buffer, 32KB LDS (R11; ~2.5 blocks/CU) — for large grids
//         where inter-block TLP hides staging latency.
// PIPE=1: double-buffer, 64KB LDS, counted-vmcnt pipeline (T3+T4): stage 2
//         tiles ahead, drain vmcnt(8) not 0, raw s_barrier + sched_barrier
//         fences, setprio around MFMA (T5) — for 2/CU-capped grids (R12).
// Requires K % 64 == 0, K >= 128 (all calls: K=2048).
// Bt2: optional second B matrix for output cols n0 >= 4096 (QKV fusion).
// MODE 0: C bf16 = acc; MODE 1: C bf16 = resid(fp32)+acc;
// MODE 2: C fp32 = resid(bf16)+acc+bias[col]
// ---------------------------------------------------------------------------
template <int MODE, int PIPE>
__global__ __launch_bounds__(256, 2) void gemm_bt(
    const ushort_t* A, int lda, const ushort_t* Bt, const ushort_t* Bt2,
    int ldb, void* Cv, int ldc, const void* resid, int ldr,
    const float* bias, int M, int N, int K) {
  constexpr int NBUF = PIPE ? 2 : 1;
  __shared__ __align__(16) ushort_t As[NBUF][128][64];
  __shared__ __align__(16) ushort_t Bs[NBUF][128][64];
  const int t = threadIdx.x;
  const int wid = t >> 6, lane = t & 63;
  const int l15 = lane & 15, quad = lane >> 4;
  const int m0 = blockIdx.y * 128, n0 = blockIdx.x * 128;
  const int wm = (wid >> 1) * 64, wn = (wid & 1) * 64;

  const ushort_t* btb = Bt;
  int nr = n0;
  if (Bt2 != nullptr && n0 >= 4096) { btb = Bt2; nr = n0 - 4096; }

  // staging: 4 calls/matrix; call s covers rows [s*32, s*32+32).
  // thread t: row = s*32 + wid*8 + (lane>>3); LDS granule = linear (s*256+t);
  // GLOBAL granule = (lane&7) ^ (row&7)  [pre-swizzled source, m173]
  const int srow = wid * 8 + (lane >> 3);
  const int scol = ((lane & 7) ^ ((lane >> 3) & 7)) * 8;
  const ushort_t* ag = &A[(size_t)(m0 + srow) * lda + scol];
  const ushort_t* bg = &btb[(size_t)(nr + srow) * ldb + scol];

  // STAGE(BUF, TILE): 8 async 16B/lane loads (4 A + 4 B), k-offset TILE*64
#define STAGE(BUF, TILE)                                                    \
  do {                                                                      \
    ushort_t* al_ = &As[BUF][wid * 8][0];                                   \
    ushort_t* bl_ = &Bs[BUF][wid * 8][0];                                   \
    const size_t ko_ = (size_t)(TILE)*64;                                   \
    load16(ag + (size_t)0 * lda + ko_,   al_ + 0 * 32 * 64);                \
    load16(ag + (size_t)32 * lda + ko_,  al_ + 1 * 32 * 64);                \
    load16(ag + (size_t)64 * lda + ko_,  al_ + 2 * 32 * 64);                \
    load16(ag + (size_t)96 * lda + ko_,  al_ + 3 * 32 * 64);                \
    load16(bg + (size_t)0 * ldb + ko_,   bl_ + 0 * 32 * 64);                \
    load16(bg + (size_t)32 * ldb + ko_,  bl_ + 1 * 32 * 64);                \
    load16(bg + (size_t)64 * ldb + ko_,  bl_ + 2 * 32 * 64);                \
    load16(bg + (size_t)96 * ldb + ko_,  bl_ + 3 * 32 * 64);                \
  } while (0)

  // COMPUTE(BUF): 32 MFMA over the 64-K tile in As/Bs[BUF]
#define COMPUTE(BUFI)                                                       \
  do {                                                                      \
    const char* asb = (const char*)&As[BUFI][0][0];                         \
    const char* bsb = (const char*)&Bs[BUFI][0][0];                         \
    _Pragma("unroll")                                                       \
    for (int kh = 0; kh < 2; ++kh) {                                        \
      const int gsel = ((kh * 4 + quad) ^ rswz) * 16;                       \
      short8 af[4], bf[4];                                                  \
      _Pragma("unroll")                                                     \
      for (int i = 0; i < 4; ++i)                                           \
        af[i] = *(const short8*)(asb + (wm + i * 16 + l15) * 128 + gsel);   \
      _Pragma("unroll")                                                     \
      for (int j = 0; j < 4; ++j)                                           \
        bf[j] = *(const short8*)(bsb + (wn + j * 16 + l15) * 128 + gsel);   \
      _Pragma("unroll")                                                     \
      for (int i = 0; i < 4; ++i)                                           \
        _Pragma("unroll")                                                   \
        for (int j = 0; j < 4; ++j)                                         \
          acc[i][j] = __builtin_amdgcn_mfma_f32_16x16x32_bf16(              \
              af[i], bf[j], acc[i][j], 0, 0, 0);                            \
    }                                                                       \
  } while (0)

  floatx4 acc[4][4];
#pragma unroll
  for (int i = 0; i < 4; ++i)
#pragma unroll
    for (int j = 0; j < 4; ++j) acc[i][j] = (floatx4){0.f, 0.f, 0.f, 0.f};

  const int rswz = (l15 & 7);  // row&7 for fragment rows wm/wn + i*16 + l15
  const int nt = K >> 6;       // K/64 tiles; nt >= 2

  if (PIPE == 0) {
    // R11 single-buffer: 2 barriers per 64-K step; TLP across ~2.5 blocks/CU
    for (int tt = 0; tt < nt; ++tt) {
      __syncthreads();
      STAGE(0, tt);
      __syncthreads();
      COMPUTE(0);
    }
  } else {
    // R12 counted-vmcnt dbuf: stage 2 ahead, never drain to 0 in steady state
    STAGE(0, 0);
    STAGE(1, 1);
    __asm__ __volatile__("s_waitcnt vmcnt(8)");
    __builtin_amdgcn_sched_barrier(0);
    __builtin_amdgcn_s_barrier();
    __builtin_amdgcn_sched_barrier(0);

    for (int tt = 0; tt < nt; ++tt) {
      const int buf = tt & 1;
      __builtin_amdgcn_s_setprio(1);
      COMPUTE(buf);
      __builtin_amdgcn_s_setprio(0);

      if (tt + 1 < nt) {
        __builtin_amdgcn_s_barrier();          // all readers of buf done
        __builtin_amdgcn_sched_barrier(0);
        if (tt + 2 < nt) {
          STAGE(buf, tt + 2);                  // refill read buffer, 2 ahead
          __asm__ __volatile__("s_waitcnt vmcnt(8)");  // tile tt+1 landed
        } else {
          __asm__ __volatile__("s_waitcnt vmcnt(0)");  // last tile landed
        }
        __builtin_amdgcn_sched_barrier(0);
        __builtin_amdgcn_s_barrier();          // tile tt+1 visible to all
        __builtin_amdgcn_sched_barrier(0);
      }
    }
  }
#undef STAGE
#undef COMPUTE

#pragma unroll
  for (int i = 0; i < 4; ++i)
#pragma unroll
    for (int j = 0; j < 4; ++j)
#pragma unroll
      for (int r = 0; r < 4; ++r) {
        int row = m0 + wm + i * 16 + quad * 4 + r;
        int col = n0 + wn + j * 16 + l15;
        float v = acc[i][j][r];
        if (MODE == 0) {
          ((ushort_t*)Cv)[(size_t)row * ldc + col] = f2bf(v);
        } else if (MODE == 1) {
          float rv = ((const float*)resid)[(size_t)row * ldr + col];
          ((ushort_t*)Cv)[(size_t)row * ldc + col] = f2bf(rv + v);
        } else {
          float rv = bf2f(((const ushort_t*)resid)[(size_t)row * ldr + col]);
          ((float*)Cv)[(size_t)row * ldc + col] = rv + v + bias[col];
        }
      }
}

// ---------------------------------------------------------------------------
// Transpose V section of qkv -> vT[b*16+h][d][s]  (bf16)
// ---------------------------------------------------------------------------
__global__ __launch_bounds__(256) void transpose_v_kernel(
    const ushort_t* __restrict__ qkv, ushort_t* __restrict__ vT) {
  __shared__ __align__(16) ushort_t tile[64][72];  // [d][s]
  const int t = threadIdx.x;
  const int s0 = blockIdx.x * 64, d0 = blockIdx.y * 64;
  const int bh = blockIdx.z, b = bh >> 4, h = bh & 15;
#pragma unroll
  for (int i = 0; i < 2; ++i) {
    int c = t + 256 * i, r = c >> 3, o = (c & 7) * 8;
    uint4 raw = *(const uint4*)&qkv[(size_t)(b * 2048 + s0 + r) * 6144 + 4096 +
                                    h * 128 + d0 + o];
    tile[o + 0][r] = (ushort_t)(raw.x & 0xffffu);
    tile[o + 1][r] = (ushort_t)(raw.x >> 16);
    tile[o + 2][r] = (ushort_t)(raw.y & 0xffffu);
    tile[o + 3][r] = (ushort_t)(raw.y >> 16);
    tile[o + 4][r] = (ushort_t)(raw.z & 0xffffu);
    tile[o + 5][r] = (ushort_t)(raw.z >> 16);
    tile[o + 6][r] = (ushort_t)(raw.w & 0xffffu);
    tile[o + 7][r] = (ushort_t)(raw.w >> 16);
  }
  __syncthreads();
#pragma unroll
  for (int i = 0; i < 2; ++i) {
    int c = t + 256 * i, r = c >> 3, o = (c & 7) * 8;
    *(uint4*)&vT[((size_t)bh * 128 + d0 + r) * 2048 + s0 + o] =
        *(const uint4*)&tile[r][o];
  }
}

// ---------------------------------------------------------------------------
// Flash attention (causal). R10 structure (unchanged):
//  - transposed QK^T -> in-lane softmax (2 shfl_xor per reduce), exp2 domain.
//  - single-barrier double-buffered K/V; staging overlaps compute.
//  - diag-only causal mask; cvt_pk P-pack; T13 defer-max.
//  - complementary q-tile pair per block (33 iters); grid 16x32, 2/CU.
// ---------------------------------------------------------------------------
__global__ __launch_bounds__(256, 2) void attn_kernel(
    const ushort_t* qkv, const ushort_t* vT, ushort_t* ctx, int ldctx) {
  const int S = 2048, LD = 6144, D = 128;
  __shared__ __align__(16) ushort_t Ks[2][64][136];
  __shared__ __align__(16) ushort_t Vt[2][128][72];
  __shared__ __align__(16) ushort_t Ps[4][16][72];
  const int t = threadIdx.x;
  const int wid = t >> 6, lane = t & 63;
  const int l15 = lane & 15, quad = lane >> 4;
  const int bx = (int)blockIdx.x;
  const int bh = blockIdx.y, b = bh >> 4, h = bh & 15;

  const int krow = t >> 4, kcol = (t & 15) * 8;   // K: 64 rows x 16 chunks, x4
  const int vrow = t >> 3, vcol = (t & 7) * 8;    // V: 128 rows x 8 chunks, x4
  const ushort_t* kgp = &qkv[(size_t)(b * S + krow) * LD + 2048 + h * D + kcol];
  const ushort_t* vgp = &vT[((size_t)bh * D + vrow) * S + vcol];

  uint4 k0r, k1r, k2r, k3r, v0r, v1r, v2r, v3r;
#define PREFETCH(KB)                                          \
  do {                                                        \
    const ushort_t* kp_ = kgp + (size_t)(KB)*LD;              \
    k0r = *(const uint4*)(kp_);                               \
    k1r = *(const uint4*)(kp_ + (size_t)16 * LD);             \
    k2r = *(const uint4*)(kp_ + (size_t)32 * LD);             \
    k3r = *(const uint4*)(kp_ + (size_t)48 * LD);             \
    const ushort_t* vp_ = vgp + (KB);                         \
    v0r = *(const uint4*)(vp_);                               \
    v1r = *(const uint4*)(vp_ + (size_t)32 * S);              \
    v2r = *(const uint4*)(vp_ + (size_t)64 * S);              \
    v3r = *(const uint4*)(vp_ + (size_t)96 * S);              \
  } while (0)
#define STAGE(BUF)                                            \
  do {                                                        \
    *(uint4*)&Ks[BUF][krow + 0][kcol]  = k0r;                 \
    *(uint4*)&Ks[BUF][krow + 16][kcol] = k1r;                 \
    *(uint4*)&Ks[BUF][krow + 32][kcol] = k2r;                 \
    *(uint4*)&Ks[BUF][krow + 48][kcol] = k3r;                 \
    *(uint4*)&Vt[BUF][vrow + 0][vcol]  = v0r;                 \
    *(uint4*)&Vt[BUF][vrow + 32][vcol] = v1r;                 \
    *(uint4*)&Vt[BUF][vrow + 64][vcol] = v2r;                 \
    *(uint4*)&Vt[BUF][vrow + 96][vcol] = v3r;                 \
  } while (0)

  const float sc2 = 0.08838834764831845f * 1.4426950408889634f;
  const int nkt0 = 32 - bx;
  const int NT = 33;

  PREFETCH(0);
  STAGE(0);
  PREFETCH(64);

  int g = 0;
  for (int ph = 0; ph < 2; ++ph) {
    const int qtile = ph == 0 ? (31 - bx) : bx;
    const int qb = qtile * 64;

    short8 qf[4];
    {
      const ushort_t* qp =
          &qkv[(size_t)(b * S + qb + wid * 16 + l15) * LD + h * D];
#pragma unroll
      for (int kk = 0; kk < 4; ++kk)
        qf[kk] = *(const short8*)&qp[kk * 32 + quad * 8];
    }

    floatx4 accO[8];
#pragma unroll
    for (int i = 0; i < 8; ++i) accO[i] = (floatx4){0.f, 0.f, 0.f, 0.f};
    float m_i = -1e30f;
    float l_i = 0.f;
    const int qg = qb + wid * 16 + l15;

    const int nkt = qtile + 1;
    for (int kt = 0; kt < nkt; ++kt, ++g) {
      const int kb = kt * 64;
      const int buf = g & 1;
      __syncthreads();
      if (g + 1 < NT) {
        STAGE(buf ^ 1);
        if (g + 2 < NT) {
          const int g2 = g + 2;
          const int kb2 = (g2 < nkt0) ? g2 * 64 : (g2 - nkt0) * 64;
          PREFETCH(kb2);
        }
      }

      floatx4 st[4];
#pragma unroll
      for (int jn = 0; jn < 4; ++jn) {
        st[jn] = (floatx4){0.f, 0.f, 0.f, 0.f};
#pragma unroll
        for (int kk = 0; kk < 4; ++kk) {
          short8 kf = *(const short8*)&Ks[buf][jn * 16 + l15][kk * 32 + quad * 8];
          st[jn] = __builtin_amdgcn_mfma_f32_16x16x32_bf16(kf, qf[kk], st[jn], 0, 0, 0);
        }
      }

      float p[4][4];
      if (kt == nkt - 1) {
#pragma unroll
        for (int jn = 0; jn < 4; ++jn)
#pragma unroll
          for (int r = 0; r < 4; ++r) {
            int kg = kb + jn * 16 + quad * 4 + r;
            float s = st[jn][r] * sc2;
            p[jn][r] = (kg <= qg) ? s : -1e30f;
          }
      } else {
#pragma unroll
        for (int jn = 0; jn < 4; ++jn)
#pragma unroll
          for (int r = 0; r < 4; ++r) p[jn][r] = st[jn][r] * sc2;
      }

      float mq0 = fmaxf(fmaxf(p[0][0], p[0][1]), fmaxf(p[0][2], p[0][3]));
      float mq1 = fmaxf(fmaxf(p[1][0], p[1][1]), fmaxf(p[1][2], p[1][3]));
      float mq2 = fmaxf(fmaxf(p[2][0], p[2][1]), fmaxf(p[2][2], p[2][3]));
      float mq3 = fmaxf(fmaxf(p[3][0], p[3][1]), fmaxf(p[3][2], p[3][3]));
      float v = fmaxf(fmaxf(mq0, mq1), fmaxf(mq2, mq3));
      v = fmaxf(v, __shfl_xor(v, 16, 64));
      v = fmaxf(v, __shfl_xor(v, 32, 64));

      if (!__all(v - m_i <= 8.0f)) {
        float mnew = fmaxf(m_i, v);
        float alpha = exp2f(m_i - mnew);
        m_i = mnew;
        float arow[4];
#pragma unroll
        for (int r = 0; r < 4; ++r) arow[r] = __shfl(alpha, quad * 4 + r, 16);
#pragma unroll
        for (int jd = 0; jd < 8; ++jd)
#pragma unroll
          for (int r = 0; r < 4; ++r) accO[jd][r] *= arow[r];
        l_i *= alpha;
      }

#pragma unroll
      for (int jn = 0; jn < 4; ++jn)
#pragma unroll
        for (int r = 0; r < 4; ++r) p[jn][r] = exp2f(p[jn][r] - m_i);

#pragma unroll
      for (int jn = 0; jn < 4; ++jn) {
        unsigned w0, w1;
        asm("v_cvt_pk_bf16_f32 %0, %1, %2" : "=v"(w0)
            : "v"(p[jn][0]), "v"(p[jn][1]));
        asm("v_cvt_pk_bf16_f32 %0, %1, %2" : "=v"(w1)
            : "v"(p[jn][2]), "v"(p[jn][3]));
        uint2 pk2; pk2.x = w0; pk2.y = w1;
        *(uint2*)&Ps[wid][l15][jn * 16 + quad * 4] = pk2;
      }

      float sq = ((p[0][0] + p[0][1]) + (p[0][2] + p[0][3])) +
                 ((p[1][0] + p[1][1]) + (p[1][2] + p[1][3])) +
                 ((p[2][0] + p[2][1]) + (p[2][2] + p[2][3])) +
                 ((p[3][0] + p[3][1]) + (p[3][2] + p[3][3]));
      sq += __shfl_xor(sq, 16, 64);
      sq += __shfl_xor(sq, 32, 64);
      l_i += sq;

      __asm__ __volatile__("s_waitcnt lgkmcnt(0)" ::: "memory");

      short8 pf[2];
#pragma unroll
      for (int kk = 0; kk < 2; ++kk)
        pf[kk] = *(const short8*)&Ps[wid][l15][kk * 32 + quad * 8];
#pragma unroll
      for (int jd = 0; jd < 8; ++jd)
#pragma unroll
        for (int kk = 0; kk < 2; ++kk) {
          short8 vf = *(const short8*)&Vt[buf][jd * 16 + l15][kk * 32 + quad * 8];
          accO[jd] = __builtin_amdgcn_mfma_f32_16x16x32_bf16(pf[kk], vf, accO[jd], 0, 0, 0);
        }
    }

    float lrow[4];
#pragma unroll
    for (int r = 0; r < 4; ++r) lrow[r] = 1.0f / __shfl(l_i, quad * 4 + r, 16);
#pragma unroll
    for (int jd = 0; jd < 8; ++jd)
#pragma unroll
      for (int r = 0; r < 4; ++r) {
        int row = b * S + qb + wid * 16 + quad * 4 + r;
        int col = h * D + jd * 16 + l15;
        ctx[(size_t)row * ldctx + col] = f2bf(accO[jd][r] * lrow[r]);
      }
  }
#undef PREFETCH
#undef STAGE
}

// ---------------------------------------------------------------------------
extern "C" void kernel_launch(void* const* d_in, const int* in_sizes, int n_in,
                              void* d_out, int out_size, void* d_ws,
                              size_t ws_size, hipStream_t stream) {
  const float* x    = (const float*)d_in[0];
  const float* ln1  = (const float*)d_in[1];
  const float* Wq   = (const float*)d_in[2];
  const float* Wk   = (const float*)d_in[3];
  const float* Wv   = (const float*)d_in[4];
  const float* Wo   = (const float*)d_in[5];
  const float* ln2  = (const float*)d_in[6];
  const float* Wmlp = (const float*)d_in[7];
  const float* bmlp = (const float*)d_in[8];
  float* out = (float*)d_out;

  char* ws = (char*)d_ws;
  ushort_t* qkv = (ushort_t*)(ws + 0);         // [4096][6144] bf16
  ushort_t* R2  = (ushort_t*)(ws + 50331648);  // 16.78 MB region
  ushort_t* WqT   = R2;                        // [2048][2048] bf16
  ushort_t* WkT   = R2 + 4194304;              // contiguous rows 2048..4095
  ushort_t* WoT   = R2;                        // after mega-GEMM (WqT dead)
  ushort_t* WmlpT = R2 + 4194304;              // coexists with WoT
  ushort_t* n1  = (ushort_t*)d_out;            // [4096][2048] bf16 scratch
  ushort_t* WvT = (ushort_t*)d_out + 8388608;  // d_out upper half
  ushort_t* vT  = (ushort_t*)d_out + 8388608;  // vT replaces WvT after mega
  ushort_t* ctx = qkv + 4096;                  // V section, ld 6144
  ushort_t* x1  = qkv + 2048;                  // K section, ld 6144
  ushort_t* n2  = qkv;                         // Q section, ld 6144

  dim3 blk(256);
  dim3 ggrid(16, 32);
  dim3 ggridQKV(48, 32);                       // fused QKV GEMM, N=6144

  // 1) rmsnorm1: x fp32 -> n1 bf16 (d_out lower half)
  rmsnorm_kernel<false><<<dim3(4096), blk, 0, stream>>>(x, 2048, ln1, n1, 2048);

  // 2) batched transpose {Wq,Wk,Wv}; WvT in d_out upper half
  transpose_w_batch<<<dim3(32, 32, 3), blk, 0, stream>>>(Wq, Wk, Wv,
                                                         WqT, WkT, WvT);
  // 3) fused QKV GEMM (PIPE=0: 1536 blocks -> TLP does the hiding; 32KB LDS)
  gemm_bt<0, 0><<<ggridQKV, blk, 0, stream>>>(n1, 2048, WqT, WvT, 2048, qkv,
                                              6144, nullptr, 0, nullptr,
                                              4096, 6144, 2048);

  // 4) batched transpose {Wo,Wmlp} into R2 (WqT/WkT dead)
  transpose_w_batch<<<dim3(32, 32, 2), blk, 0, stream>>>(Wo, Wmlp, Wo,
                                                         WoT, WmlpT, WoT);

  // 5) V transpose into d_out upper half (WvT dead)
  transpose_v_kernel<<<dim3(32, 2, 32), blk, 0, stream>>>(qkv, vT);

  // 6) causal flash attention -> ctx (overwrites dead V section)
  attn_kernel<<<dim3(16, 32), blk, 0, stream>>>(qkv, vT, ctx, 6144);

  // 7) out-projection + residual(x) -> x1 (PIPE=1: 512 blocks, 2/CU-capped)
  gemm_bt<1, 1><<<ggrid, blk, 0, stream>>>(ctx, 6144, WoT, nullptr, 2048, x1,
                                           6144, x, 2048, nullptr,
                                           4096, 2048, 2048);

  // 8) rmsnorm2: x1 -> n2 (dead Q section)
  rmsnorm_kernel<true><<<dim3(4096), blk, 0, stream>>>(x1, 6144, ln2, n2, 6144);

  // 9) MLP + residual + bias -> out fp32 (PIPE=1)
  gemm_bt<2, 1><<<ggrid, blk, 0, stream>>>(n2, 6144, WmlpT, nullptr, 2048, out,
                                           2048, x1, 6144, bmlp,
                                           4096, 2048, 2048);
}

// Round 11
// 458.233 us; speedup vs baseline: 1.0088x; 1.0088x over previous
//
#include <hip/hip_runtime.h>

// TinyLlamaBlock on MI355X (gfx950). Inputs fp32, output fp32 (validated R5).
// Internal compute bf16 via v_mfma_f32_16x16x32_bf16, fp32 accumulate.
// R14: revert to R12's all-dbuf GEMM (best measured total 453.8us; R13's
// dual-pipeline template cost the tails ~33us — rule #19 co-instantiation
// perturbation) + T1 XCD-aware block swizzle in gemm_bt: consecutive blocks
// share a 512KB A-panel but round-robin XCD L2s by default (mega FETCH
// 106.6MB vs ~42MB ideal). swz=(orig&7)*(nwg/8)+orig/8 (bijective: all
// grids nwg%8==0) gives each XCD a contiguous 4-M-row chunk -> A-panels
// stay L2-resident. Attn unchanged from R10.
//
// Workspace (67.11 MB):
//   [0, 50331648)        qkv bf16 [4096][6144]: cols [0,2048)=Q (later n2),
//                        [2048,4096)=K (later x1), [4096,6144)=V (later ctx)
//   [50331648, 67108864) R2 16.78 MB: WqT|WkT -> (after mega) WoT|WmlpT
// d_out (33.55 MB): lower n1 bf16 [4096][2048]; upper WvT bf16 [2048][2048]
// -> vT [32][128][2048] (after mega-GEMM); final GEMM rewrites all as fp32.

typedef unsigned short ushort_t;
typedef __attribute__((ext_vector_type(8))) short short8;
typedef __attribute__((ext_vector_type(4))) float floatx4;

__device__ __forceinline__ ushort_t f2bf(float f) {
  union { float f; unsigned u; } v; v.f = f;
  unsigned r = v.u + 0x7fffu + ((v.u >> 16) & 1u);  // RNE
  return (ushort_t)(r >> 16);
}
__device__ __forceinline__ float bf2f(unsigned h) {
  union { unsigned u; float f; } v; v.u = h << 16; return v.f;
}
// async 16B/lane global->LDS; LDS dest = wave-uniform base + lane*16
__device__ __forceinline__ void load16(const ushort_t* g, ushort_t* l) {
  __builtin_amdgcn_global_load_lds(
      (const __attribute__((address_space(1))) unsigned*)g,
      (__attribute__((address_space(3))) unsigned*)l, 16, 0, 0);
}

// ---------------------------------------------------------------------------
// Batched weight transpose+convert: fp32 [2048][2048] (k,n) -> bf16 (n,k).
// blockIdx.z selects which (src,dst) pair.
// ---------------------------------------------------------------------------
__global__ __launch_bounds__(256) void transpose_w_batch(
    const float* __restrict__ s0, const float* __restrict__ s1,
    const float* __restrict__ s2, ushort_t* __restrict__ d0,
    ushort_t* __restrict__ d1, ushort_t* __restrict__ d2) {
  __shared__ __align__(16) ushort_t tile[64][72];  // [n][k]
  const float* src = s0;
  ushort_t* dst = d0;
  if (blockIdx.z == 1) { src = s1; dst = d1; }
  else if (blockIdx.z == 2) { src = s2; dst = d2; }
  const int t = threadIdx.x;
  const int n0 = blockIdx.x * 64, k0 = blockIdx.y * 64;
#pragma unroll
  for (int i = 0; i < 4; ++i) {
    int c = t + 256 * i;            // 64 k-rows x 16 chunks of 4 floats
    int r = c >> 4, o = (c & 15) * 4;
    float4 raw = *(const float4*)&src[(size_t)(k0 + r) * 2048 + n0 + o];
    tile[o + 0][r] = f2bf(raw.x);
    tile[o + 1][r] = f2bf(raw.y);
    tile[o + 2][r] = f2bf(raw.z);
    tile[o + 3][r] = f2bf(raw.w);
  }
  __syncthreads();
#pragma unroll
  for (int i = 0; i < 2; ++i) {
    int c = t + 256 * i;            // 64 n-rows x 8 chunks of 8 bf16
    int r = c >> 3, o = (c & 7) * 8;
    *(uint4*)&dst[(size_t)(n0 + r) * 2048 + k0 + o] = *(const uint4*)&tile[r][o];
  }
}

// ---------------------------------------------------------------------------
// RMSNorm [4096][2048] -> bf16 (strided in/out). XBF: input bf16 else fp32.
// ---------------------------------------------------------------------------
template <bool XBF>
__global__ __launch_bounds__(256) void rmsnorm_kernel(
    const void* __restrict__ xv, int in_ld, const float* __restrict__ g,
    ushort_t* __restrict__ out, int out_ld) {
  const int row = blockIdx.x, t = threadIdx.x;
  float v[8];
  if (XBF) {
    uint4 raw = *(const uint4*)((const ushort_t*)xv + (size_t)row * in_ld + t * 8);
    v[0] = bf2f(raw.x & 0xffffu); v[1] = bf2f(raw.x >> 16);
    v[2] = bf2f(raw.y & 0xffffu); v[3] = bf2f(raw.y >> 16);
    v[4] = bf2f(raw.z & 0xffffu); v[5] = bf2f(raw.z >> 16);
    v[6] = bf2f(raw.w & 0xffffu); v[7] = bf2f(raw.w >> 16);
  } else {
    const float* xr = (const float*)xv + (size_t)row * in_ld + t * 8;
    float4 a = *(const float4*)xr;
    float4 b = *(const float4*)(xr + 4);
    v[0] = a.x; v[1] = a.y; v[2] = a.z; v[3] = a.w;
    v[4] = b.x; v[5] = b.y; v[6] = b.z; v[7] = b.w;
  }
  float ss = 0.f;
#pragma unroll
  for (int i = 0; i < 8; ++i) ss += v[i] * v[i];
#pragma unroll
  for (int m = 32; m >= 1; m >>= 1) ss += __shfl_xor(ss, m, 64);
  __shared__ float red[4];
  if ((t & 63) == 0) red[t >> 6] = ss;
  __syncthreads();
  float rs = rsqrtf((red[0] + red[1] + red[2] + red[3]) * (1.0f / 2048.0f) + 1e-5f);
  const float* gp = g + t * 8;
  float4 ga = *(const float4*)gp;
  float4 gb = *(const float4*)(gp + 4);
  float gv[8] = {ga.x, ga.y, ga.z, ga.w, gb.x, gb.y, gb.z, gb.w};
  union { ushort_t u16[8]; uint4 u; } p;
#pragma unroll
  for (int i = 0; i < 8; ++i) p.u16[i] = f2bf(v[i] * rs * gv[i]);
  *(uint4*)&out[(size_t)row * out_ld + t * 8] = p.u;
}

// ---------------------------------------------------------------------------
// GEMM: C[M,N] = A[M,K](bf16, lda) * Bt[N,K](bf16, ldb)^T.
// R12 structure: 128x128 tile, BK=64, DOUBLE-buffered swizzled LDS,
// counted-vmcnt pipeline (T3+T4): stage 2 tiles ahead, drain vmcnt(8) not 0,
// raw s_barrier + sched_barrier(0) fences, setprio(1) around MFMA (T5).
// R14: + T1 XCD-aware block swizzle (requires nwg % 8 == 0 — all calls OK):
// dispatched block orig does logical tile swz=(orig&7)*(nwg/8)+orig/8, so
// each XCD L2 owns a contiguous run of tiles sharing A-panels.
// LDS staging keeps LINEAR gload_lds dest; each lane's GLOBAL source fetches
// granule g^(row&7); fragment reads apply the same XOR (R11, conflicts=0).
// Requires K % 64 == 0, K >= 128 (all calls: K=2048).
// Bt2: optional second B matrix for output cols n0 >= 4096 (QKV fusion).
// MODE 0: C bf16 = acc; MODE 1: C bf16 = resid(fp32)+acc;
// MODE 2: C fp32 = resid(bf16)+acc+bias[col]
// ---------------------------------------------------------------------------
template <int MODE>
__global__ __launch_bounds__(256, 2) void gemm_bt(
    const ushort_t* A, int lda, const ushort_t* Bt, const ushort_t* Bt2,
    int ldb, void* Cv, int ldc, const void* resid, int ldr,
    const float* bias, int M, int N, int K) {
  __shared__ __align__(16) ushort_t As[2][128][64];
  __shared__ __align__(16) ushort_t Bs[2][128][64];
  const int t = threadIdx.x;
  const int wid = t >> 6, lane = t & 63;
  const int l15 = lane & 15, quad = lane >> 4;

  // T1 XCD swizzle: contiguous logical-tile chunk per XCD (nwg % 8 == 0)
  const int gdx = (int)gridDim.x;
  const int nwg = gdx * (int)gridDim.y;
  const int orig = (int)blockIdx.y * gdx + (int)blockIdx.x;
  const int swz = (orig & 7) * (nwg >> 3) + (orig >> 3);
  const int m0 = (swz / gdx) * 128, n0 = (swz % gdx) * 128;
  const int wm = (wid >> 1) * 64, wn = (wid & 1) * 64;

  const ushort_t* btb = Bt;
  int nr = n0;
  if (Bt2 != nullptr && n0 >= 4096) { btb = Bt2; nr = n0 - 4096; }

  // staging: 4 calls/matrix; call s covers rows [s*32, s*32+32).
  // thread t: row = s*32 + wid*8 + (lane>>3); LDS granule = linear (s*256+t);
  // GLOBAL granule = (lane&7) ^ (row&7)  [pre-swizzled source, m173]
  const int srow = wid * 8 + (lane >> 3);
  const int scol = ((lane & 7) ^ ((lane >> 3) & 7)) * 8;
  const ushort_t* ag = &A[(size_t)(m0 + srow) * lda + scol];
  const ushort_t* bg = &btb[(size_t)(nr + srow) * ldb + scol];

  // STAGE(BUF, TILE): 8 async 16B/lane loads (4 A + 4 B), k-offset TILE*64
#define STAGE(BUF, TILE)                                                    \
  do {                                                                      \
    ushort_t* al_ = &As[BUF][wid * 8][0];                                   \
    ushort_t* bl_ = &Bs[BUF][wid * 8][0];                                   \
    const size_t ko_ = (size_t)(TILE)*64;                                   \
    load16(ag + (size_t)0 * lda + ko_,   al_ + 0 * 32 * 64);                \
    load16(ag + (size_t)32 * lda + ko_,  al_ + 1 * 32 * 64);                \
    load16(ag + (size_t)64 * lda + ko_,  al_ + 2 * 32 * 64);                \
    load16(ag + (size_t)96 * lda + ko_,  al_ + 3 * 32 * 64);                \
    load16(bg + (size_t)0 * ldb + ko_,   bl_ + 0 * 32 * 64);                \
    load16(bg + (size_t)32 * ldb + ko_,  bl_ + 1 * 32 * 64);                \
    load16(bg + (size_t)64 * ldb + ko_,  bl_ + 2 * 32 * 64);                \
    load16(bg + (size_t)96 * ldb + ko_,  bl_ + 3 * 32 * 64);                \
  } while (0)

  floatx4 acc[4][4];
#pragma unroll
  for (int i = 0; i < 4; ++i)
#pragma unroll
    for (int j = 0; j < 4; ++j) acc[i][j] = (floatx4){0.f, 0.f, 0.f, 0.f};

  const int rswz = (l15 & 7);  // row&7 for fragment rows wm/wn + i*16 + l15
  const int nt = K >> 6;       // K/64 tiles; nt >= 2

  // prologue: tiles 0 and 1 in flight; wait tile 0 (vmcnt(8): 8 newest fly)
  STAGE(0, 0);
  STAGE(1, 1);
  __asm__ __volatile__("s_waitcnt vmcnt(8)");
  __builtin_amdgcn_sched_barrier(0);
  __builtin_amdgcn_s_barrier();
  __builtin_amdgcn_sched_barrier(0);

  for (int tt = 0; tt < nt; ++tt) {
    const int buf = tt & 1;
    const char* asb = (const char*)&As[buf][0][0];
    const char* bsb = (const char*)&Bs[buf][0][0];
    __builtin_amdgcn_s_setprio(1);
#pragma unroll
    for (int kh = 0; kh < 2; ++kh) {
      const int gsel = ((kh * 4 + quad) ^ rswz) * 16;  // physical granule byte
      short8 af[4], bf[4];
#pragma unroll
      for (int i = 0; i < 4; ++i)
        af[i] = *(const short8*)(asb + (wm + i * 16 + l15) * 128 + gsel);
#pragma unroll
      for (int j = 0; j < 4; ++j)
        bf[j] = *(const short8*)(bsb + (wn + j * 16 + l15) * 128 + gsel);
#pragma unroll
      for (int i = 0; i < 4; ++i)
#pragma unroll
        for (int j = 0; j < 4; ++j)
          acc[i][j] = __builtin_amdgcn_mfma_f32_16x16x32_bf16(af[i], bf[j],
                                                              acc[i][j], 0, 0, 0);
    }
    __builtin_amdgcn_s_setprio(0);

    if (tt + 1 < nt) {
      __builtin_amdgcn_s_barrier();          // all readers of buf done
      __builtin_amdgcn_sched_barrier(0);
      if (tt + 2 < nt) {
        STAGE(buf, tt + 2);                  // refill read buffer, 2 ahead
        __asm__ __volatile__("s_waitcnt vmcnt(8)");  // tile tt+1 landed
      } else {
        __asm__ __volatile__("s_waitcnt vmcnt(0)");  // last tile landed
      }
      __builtin_amdgcn_sched_barrier(0);
      __builtin_amdgcn_s_barrier();          // tile tt+1 visible to all
      __builtin_amdgcn_sched_barrier(0);
    }
  }
#undef STAGE

#pragma unroll
  for (int i = 0; i < 4; ++i)
#pragma unroll
    for (int j = 0; j < 4; ++j)
#pragma unroll
      for (int r = 0; r < 4; ++r) {
        int row = m0 + wm + i * 16 + quad * 4 + r;
        int col = n0 + wn + j * 16 + l15;
        float v = acc[i][j][r];
        if (MODE == 0) {
          ((ushort_t*)Cv)[(size_t)row * ldc + col] = f2bf(v);
        } else if (MODE == 1) {
          float rv = ((const float*)resid)[(size_t)row * ldr + col];
          ((ushort_t*)Cv)[(size_t)row * ldc + col] = f2bf(rv + v);
        } else {
          float rv = bf2f(((const ushort_t*)resid)[(size_t)row * ldr + col]);
          ((float*)Cv)[(size_t)row * ldc + col] = rv + v + bias[col];
        }
      }
}

// ---------------------------------------------------------------------------
// Transpose V section of qkv -> vT[b*16+h][d][s]  (bf16)
// ---------------------------------------------------------------------------
__global__ __launch_bounds__(256) void transpose_v_kernel(
    const ushort_t* __restrict__ qkv, ushort_t* __restrict__ vT) {
  __shared__ __align__(16) ushort_t tile[64][72];  // [d][s]
  const int t = threadIdx.x;
  const int s0 = blockIdx.x * 64, d0 = blockIdx.y * 64;
  const int bh = blockIdx.z, b = bh >> 4, h = bh & 15;
#pragma unroll
  for (int i = 0; i < 2; ++i) {
    int c = t + 256 * i, r = c >> 3, o = (c & 7) * 8;
    uint4 raw = *(const uint4*)&qkv[(size_t)(b * 2048 + s0 + r) * 6144 + 4096 +
                                    h * 128 + d0 + o];
    tile[o + 0][r] = (ushort_t)(raw.x & 0xffffu);
    tile[o + 1][r] = (ushort_t)(raw.x >> 16);
    tile[o + 2][r] = (ushort_t)(raw.y & 0xffffu);
    tile[o + 3][r] = (ushort_t)(raw.y >> 16);
    tile[o + 4][r] = (ushort_t)(raw.z & 0xffffu);
    tile[o + 5][r] = (ushort_t)(raw.z >> 16);
    tile[o + 6][r] = (ushort_t)(raw.w & 0xffffu);
    tile[o + 7][r] = (ushort_t)(raw.w >> 16);
  }
  __syncthreads();
#pragma unroll
  for (int i = 0; i < 2; ++i) {
    int c = t + 256 * i, r = c >> 3, o = (c & 7) * 8;
    *(uint4*)&vT[((size_t)bh * 128 + d0 + r) * 2048 + s0 + o] =
        *(const uint4*)&tile[r][o];
  }
}

// ---------------------------------------------------------------------------
// Flash attention (causal). R10 structure (unchanged):
//  - transposed QK^T -> in-lane softmax (2 shfl_xor per reduce), exp2 domain.
//  - single-barrier double-buffered K/V; staging overlaps compute.
//  - diag-only causal mask; cvt_pk P-pack; T13 defer-max.
//  - complementary q-tile pair per block (33 iters); grid 16x32, 2/CU.
// ---------------------------------------------------------------------------
__global__ __launch_bounds__(256, 2) void attn_kernel(
    const ushort_t* qkv, const ushort_t* vT, ushort_t* ctx, int ldctx) {
  const int S = 2048, LD = 6144, D = 128;
  __shared__ __align__(16) ushort_t Ks[2][64][136];
  __shared__ __align__(16) ushort_t Vt[2][128][72];
  __shared__ __align__(16) ushort_t Ps[4][16][72];
  const int t = threadIdx.x;
  const int wid = t >> 6, lane = t & 63;
  const int l15 = lane & 15, quad = lane >> 4;
  const int bx = (int)blockIdx.x;
  const int bh = blockIdx.y, b = bh >> 4, h = bh & 15;

  const int krow = t >> 4, kcol = (t & 15) * 8;   // K: 64 rows x 16 chunks, x4
  const int vrow = t >> 3, vcol = (t & 7) * 8;    // V: 128 rows x 8 chunks, x4
  const ushort_t* kgp = &qkv[(size_t)(b * S + krow) * LD + 2048 + h * D + kcol];
  const ushort_t* vgp = &vT[((size_t)bh * D + vrow) * S + vcol];

  uint4 k0r, k1r, k2r, k3r, v0r, v1r, v2r, v3r;
#define PREFETCH(KB)                                          \
  do {                                                        \
    const ushort_t* kp_ = kgp + (size_t)(KB)*LD;              \
    k0r = *(const uint4*)(kp_);                               \
    k1r = *(const uint4*)(kp_ + (size_t)16 * LD);             \
    k2r = *(const uint4*)(kp_ + (size_t)32 * LD);             \
    k3r = *(const uint4*)(kp_ + (size_t)48 * LD);             \
    const ushort_t* vp_ = vgp + (KB);                         \
    v0r = *(const uint4*)(vp_);                               \
    v1r = *(const uint4*)(vp_ + (size_t)32 * S);              \
    v2r = *(const uint4*)(vp_ + (size_t)64 * S);              \
    v3r = *(const uint4*)(vp_ + (size_t)96 * S);              \
  } while (0)
#define STAGE(BUF)                                            \
  do {                                                        \
    *(uint4*)&Ks[BUF][krow + 0][kcol]  = k0r;                 \
    *(uint4*)&Ks[BUF][krow + 16][kcol] = k1r;                 \
    *(uint4*)&Ks[BUF][krow + 32][kcol] = k2r;                 \
    *(uint4*)&Ks[BUF][krow + 48][kcol] = k3r;                 \
    *(uint4*)&Vt[BUF][vrow + 0][vcol]  = v0r;                 \
    *(uint4*)&Vt[BUF][vrow + 32][vcol] = v1r;                 \
    *(uint4*)&Vt[BUF][vrow + 64][vcol] = v2r;                 \
    *(uint4*)&Vt[BUF][vrow + 96][vcol] = v3r;                 \
  } while (0)

  const float sc2 = 0.08838834764831845f * 1.4426950408889634f;
  const int nkt0 = 32 - bx;
  const int NT = 33;

  PREFETCH(0);
  STAGE(0);
  PREFETCH(64);

  int g = 0;
  for (int ph = 0; ph < 2; ++ph) {
    const int qtile = ph == 0 ? (31 - bx) : bx;
    const int qb = qtile * 64;

    short8 qf[4];
    {
      const ushort_t* qp =
          &qkv[(size_t)(b * S + qb + wid * 16 + l15) * LD + h * D];
#pragma unroll
      for (int kk = 0; kk < 4; ++kk)
        qf[kk] = *(const short8*)&qp[kk * 32 + quad * 8];
    }

    floatx4 accO[8];
#pragma unroll
    for (int i = 0; i < 8; ++i) accO[i] = (floatx4){0.f, 0.f, 0.f, 0.f};
    float m_i = -1e30f;
    float l_i = 0.f;
    const int qg = qb + wid * 16 + l15;

    const int nkt = qtile + 1;
    for (int kt = 0; kt < nkt; ++kt, ++g) {
      const int kb = kt * 64;
      const int buf = g & 1;
      __syncthreads();
      if (g + 1 < NT) {
        STAGE(buf ^ 1);
        if (g + 2 < NT) {
          const int g2 = g + 2;
          const int kb2 = (g2 < nkt0) ? g2 * 64 : (g2 - nkt0) * 64;
          PREFETCH(kb2);
        }
      }

      floatx4 st[4];
#pragma unroll
      for (int jn = 0; jn < 4; ++jn) {
        st[jn] = (floatx4){0.f, 0.f, 0.f, 0.f};
#pragma unroll
        for (int kk = 0; kk < 4; ++kk) {
          short8 kf = *(const short8*)&Ks[buf][jn * 16 + l15][kk * 32 + quad * 8];
          st[jn] = __builtin_amdgcn_mfma_f32_16x16x32_bf16(kf, qf[kk], st[jn], 0, 0, 0);
        }
      }

      float p[4][4];
      if (kt == nkt - 1) {
#pragma unroll
        for (int jn = 0; jn < 4; ++jn)
#pragma unroll
          for (int r = 0; r < 4; ++r) {
            int kg = kb + jn * 16 + quad * 4 + r;
            float s = st[jn][r] * sc2;
            p[jn][r] = (kg <= qg) ? s : -1e30f;
          }
      } else {
#pragma unroll
        for (int jn = 0; jn < 4; ++jn)
#pragma unroll
          for (int r = 0; r < 4; ++r) p[jn][r] = st[jn][r] * sc2;
      }

      float mq0 = fmaxf(fmaxf(p[0][0], p[0][1]), fmaxf(p[0][2], p[0][3]));
      float mq1 = fmaxf(fmaxf(p[1][0], p[1][1]), fmaxf(p[1][2], p[1][3]));
      float mq2 = fmaxf(fmaxf(p[2][0], p[2][1]), fmaxf(p[2][2], p[2][3]));
      float mq3 = fmaxf(fmaxf(p[3][0], p[3][1]), fmaxf(p[3][2], p[3][3]));
      float v = fmaxf(fmaxf(mq0, mq1), fmaxf(mq2, mq3));
      v = fmaxf(v, __shfl_xor(v, 16, 64));
      v = fmaxf(v, __shfl_xor(v, 32, 64));

      if (!__all(v - m_i <= 8.0f)) {
        float mnew = fmaxf(m_i, v);
        float alpha = exp2f(m_i - mnew);
        m_i = mnew;
        float arow[4];
#pragma unroll
        for (int r = 0; r < 4; ++r) arow[r] = __shfl(alpha, quad * 4 + r, 16);
#pragma unroll
        for (int jd = 0; jd < 8; ++jd)
#pragma unroll
          for (int r = 0; r < 4; ++r) accO[jd][r] *= arow[r];
        l_i *= alpha;
      }

#pragma unroll
      for (int jn = 0; jn < 4; ++jn)
#pragma unroll
        for (int r = 0; r < 4; ++r) p[jn][r] = exp2f(p[jn][r] - m_i);

#pragma unroll
      for (int jn = 0; jn < 4; ++jn) {
        unsigned w0, w1;
        asm("v_cvt_pk_bf16_f32 %0, %1, %2" : "=v"(w0)
            : "v"(p[jn][0]), "v"(p[jn][1]));
        asm("v_cvt_pk_bf16_f32 %0, %1, %2" : "=v"(w1)
            : "v"(p[jn][2]), "v"(p[jn][3]));
        uint2 pk2; pk2.x = w0; pk2.y = w1;
        *(uint2*)&Ps[wid][l15][jn * 16 + quad * 4] = pk2;
      }

      float sq = ((p[0][0] + p[0][1]) + (p[0][2] + p[0][3])) +
                 ((p[1][0] + p[1][1]) + (p[1][2] + p[1][3])) +
                 ((p[2][0] + p[2][1]) + (p[2][2] + p[2][3])) +
                 ((p[3][0] + p[3][1]) + (p[3][2] + p[3][3]));
      sq += __shfl_xor(sq, 16, 64);
      sq += __shfl_xor(sq, 32, 64);
      l_i += sq;

      __asm__ __volatile__("s_waitcnt lgkmcnt(0)" ::: "memory");

      short8 pf[2];
#pragma unroll
      for (int kk = 0; kk < 2; ++kk)
        pf[kk] = *(const short8*)&Ps[wid][l15][kk * 32 + quad * 8];
#pragma unroll
      for (int jd = 0; jd < 8; ++jd)
#pragma unroll
        for (int kk = 0; kk < 2; ++kk) {
          short8 vf = *(const short8*)&Vt[buf][jd * 16 + l15][kk * 32 + quad * 8];
          accO[jd] = __builtin_amdgcn_mfma_f32_16x16x32_bf16(pf[kk], vf, accO[jd], 0, 0, 0);
        }
    }

    float lrow[4];
#pragma unroll
    for (int r = 0; r < 4; ++r) lrow[r] = 1.0f / __shfl(l_i, quad * 4 + r, 16);
#pragma unroll
    for (int jd = 0; jd < 8; ++jd)
#pragma unroll
      for (int r = 0; r < 4; ++r) {
        int row = b * S + qb + wid * 16 + quad * 4 + r;
        int col = h * D + jd * 16 + l15;
        ctx[(size_t)row * ldctx + col] = f2bf(accO[jd][r] * lrow[r]);
      }
  }
#undef PREFETCH
#undef STAGE
}

// ---------------------------------------------------------------------------
extern "C" void kernel_launch(void* const* d_in, const int* in_sizes, int n_in,
                              void* d_out, int out_size, void* d_ws,
                              size_t ws_size, hipStream_t stream) {
  const float* x    = (const float*)d_in[0];
  const float* ln1  = (const float*)d_in[1];
  const float* Wq   = (const float*)d_in[2];
  const float* Wk   = (const float*)d_in[3];
  const float* Wv   = (const float*)d_in[4];
  const float* Wo   = (const float*)d_in[5];
  const float* ln2  = (const float*)d_in[6];
  const float* Wmlp = (const float*)d_in[7];
  const float* bmlp = (const float*)d_in[8];
  float* out = (float*)d_out;

  char* ws = (char*)d_ws;
  ushort_t* qkv = (ushort_t*)(ws + 0);         // [4096][6144] bf16
  ushort_t* R2  = (ushort_t*)(ws + 50331648);  // 16.78 MB region
  ushort_t* WqT   = R2;                        // [2048][2048] bf16
  ushort_t* WkT   = R2 + 4194304;              // contiguous rows 2048..4095
  ushort_t* WoT   = R2;                        // after mega-GEMM (WqT dead)
  ushort_t* WmlpT = R2 + 4194304;              // coexists with WoT
  ushort_t* n1  = (ushort_t*)d_out;            // [4096][2048] bf16 scratch
  ushort_t* WvT = (ushort_t*)d_out + 8388608;  // d_out upper half
  ushort_t* vT  = (ushort_t*)d_out + 8388608;  // vT replaces WvT after mega
  ushort_t* ctx = qkv + 4096;                  // V section, ld 6144
  ushort_t* x1  = qkv + 2048;                  // K section, ld 6144
  ushort_t* n2  = qkv;                         // Q section, ld 6144

  dim3 blk(256);
  dim3 ggrid(16, 32);
  dim3 ggridQKV(48, 32);                       // fused QKV GEMM, N=6144

  // 1) rmsnorm1: x fp32 -> n1 bf16 (d_out lower half)
  rmsnorm_kernel<false><<<dim3(4096), blk, 0, stream>>>(x, 2048, ln1, n1, 2048);

  // 2) batched transpose {Wq,Wk,Wv}; WvT in d_out upper half
  transpose_w_batch<<<dim3(32, 32, 3), blk, 0, stream>>>(Wq, Wk, Wv,
                                                         WqT, WkT, WvT);
  // 3) fused QKV GEMM: Bt rows 0..4095 = WqT|WkT (R2), rows 4096..6143 = WvT
  gemm_bt<0><<<ggridQKV, blk, 0, stream>>>(n1, 2048, WqT, WvT, 2048, qkv, 6144,
                                           nullptr, 0, nullptr, 4096, 6144, 2048);

  // 4) batched transpose {Wo,Wmlp} into R2 (WqT/WkT dead)
  transpose_w_batch<<<dim3(32, 32, 2), blk, 0, stream>>>(Wo, Wmlp, Wo,
                                                         WoT, WmlpT, WoT);

  // 5) V transpose into d_out upper half (WvT dead)
  transpose_v_kernel<<<dim3(32, 2, 32), blk, 0, stream>>>(qkv, vT);

  // 6) causal flash attention -> ctx (overwrites dead V section)
  attn_kernel<<<dim3(16, 32), blk, 0, stream>>>(qkv, vT, ctx, 6144);

  // 7) out-projection + residual(x) -> x1 bf16 into dead K section
  gemm_bt<1><<<ggrid, blk, 0, stream>>>(ctx, 6144, WoT, nullptr, 2048, x1, 6144,
                                        x, 2048, nullptr, 4096, 2048, 2048);

  // 8) rmsnorm2: x1 -> n2 (dead Q section)
  rmsnorm_kernel<true><<<dim3(4096), blk, 0, stream>>>(x1, 6144, ln2, n2, 6144);

  // 9) MLP + residual(x1 bf16) + bias -> out fp32 (n1/vT dead)
  gemm_bt<2><<<ggrid, blk, 0, stream>>>(n2, 6144, WmlpT, nullptr, 2048, out, 2048,
                                        x1, 6144, bmlp, 4096, 2048, 2048);
}

// Round 12
// 450.938 us; speedup vs baseline: 1.0251x; 1.0162x over previous
//
#include <hip/hip_runtime.h>

// TinyLlamaBlock on MI355X (gfx950). Inputs fp32, output fp32 (validated R5).
// Internal compute bf16 via v_mfma_f32_16x16x32_bf16, fp32 accumulate.
// R15: (a) drop R14's XCD swizzle (FETCH 106->307MB, -4.4us: contiguous-chunk
// mapping made each XCD stream all of B per M-row; L3 absorbed it but net
// loss). (b) collect BOTH GEMM wins via two SEPARATE NAMED kernels (not a
// shared template — R13's hybrid lost the tails' dbuf gain, rule #19
// co-instantiation perturbation): gemm_mega = R11 single-buffer BK=64
// (32KB LDS, ~2.6 blocks/CU, 99.4us measured) for the 1536-block mega;
// gemm_tail<1|2> = R12 counted-vmcnt dbuf (64KB LDS) for the 512-block
// residency-capped tails (R12 evidence: -33us combined vs single-buffer).
// Attn unchanged from R10.
//
// Workspace (67.11 MB):
//   [0, 50331648)        qkv bf16 [4096][6144]: cols [0,2048)=Q (later n2),
//                        [2048,4096)=K (later x1), [4096,6144)=V (later ctx)
//   [50331648, 67108864) R2 16.78 MB: WqT|WkT -> (after mega) WoT|WmlpT
// d_out (33.55 MB): lower n1 bf16 [4096][2048]; upper WvT bf16 [2048][2048]
// -> vT [32][128][2048] (after mega-GEMM); final GEMM rewrites all as fp32.

typedef unsigned short ushort_t;
typedef __attribute__((ext_vector_type(8))) short short8;
typedef __attribute__((ext_vector_type(4))) float floatx4;

__device__ __forceinline__ ushort_t f2bf(float f) {
  union { float f; unsigned u; } v; v.f = f;
  unsigned r = v.u + 0x7fffu + ((v.u >> 16) & 1u);  // RNE
  return (ushort_t)(r >> 16);
}
__device__ __forceinline__ float bf2f(unsigned h) {
  union { unsigned u; float f; } v; v.u = h << 16; return v.f;
}
// async 16B/lane global->LDS; LDS dest = wave-uniform base + lane*16
__device__ __forceinline__ void load16(const ushort_t* g, ushort_t* l) {
  __builtin_amdgcn_global_load_lds(
      (const __attribute__((address_space(1))) unsigned*)g,
      (__attribute__((address_space(3))) unsigned*)l, 16, 0, 0);
}

// ---------------------------------------------------------------------------
// Batched weight transpose+convert: fp32 [2048][2048] (k,n) -> bf16 (n,k).
// blockIdx.z selects which (src,dst) pair.
// ---------------------------------------------------------------------------
__global__ __launch_bounds__(256) void transpose_w_batch(
    const float* __restrict__ s0, const float* __restrict__ s1,
    const float* __restrict__ s2, ushort_t* __restrict__ d0,
    ushort_t* __restrict__ d1, ushort_t* __restrict__ d2) {
  __shared__ __align__(16) ushort_t tile[64][72];  // [n][k]
  const float* src = s0;
  ushort_t* dst = d0;
  if (blockIdx.z == 1) { src = s1; dst = d1; }
  else if (blockIdx.z == 2) { src = s2; dst = d2; }
  const int t = threadIdx.x;
  const int n0 = blockIdx.x * 64, k0 = blockIdx.y * 64;
#pragma unroll
  for (int i = 0; i < 4; ++i) {
    int c = t + 256 * i;            // 64 k-rows x 16 chunks of 4 floats
    int r = c >> 4, o = (c & 15) * 4;
    float4 raw = *(const float4*)&src[(size_t)(k0 + r) * 2048 + n0 + o];
    tile[o + 0][r] = f2bf(raw.x);
    tile[o + 1][r] = f2bf(raw.y);
    tile[o + 2][r] = f2bf(raw.z);
    tile[o + 3][r] = f2bf(raw.w);
  }
  __syncthreads();
#pragma unroll
  for (int i = 0; i < 2; ++i) {
    int c = t + 256 * i;            // 64 n-rows x 8 chunks of 8 bf16
    int r = c >> 3, o = (c & 7) * 8;
    *(uint4*)&dst[(size_t)(n0 + r) * 2048 + k0 + o] = *(const uint4*)&tile[r][o];
  }
}

// ---------------------------------------------------------------------------
// RMSNorm [4096][2048] -> bf16 (strided in/out). XBF: input bf16 else fp32.
// ---------------------------------------------------------------------------
template <bool XBF>
__global__ __launch_bounds__(256) void rmsnorm_kernel(
    const void* __restrict__ xv, int in_ld, const float* __restrict__ g,
    ushort_t* __restrict__ out, int out_ld) {
  const int row = blockIdx.x, t = threadIdx.x;
  float v[8];
  if (XBF) {
    uint4 raw = *(const uint4*)((const ushort_t*)xv + (size_t)row * in_ld + t * 8);
    v[0] = bf2f(raw.x & 0xffffu); v[1] = bf2f(raw.x >> 16);
    v[2] = bf2f(raw.y & 0xffffu); v[3] = bf2f(raw.y >> 16);
    v[4] = bf2f(raw.z & 0xffffu); v[5] = bf2f(raw.z >> 16);
    v[6] = bf2f(raw.w & 0xffffu); v[7] = bf2f(raw.w >> 16);
  } else {
    const float* xr = (const float*)xv + (size_t)row * in_ld + t * 8;
    float4 a = *(const float4*)xr;
    float4 b = *(const float4*)(xr + 4);
    v[0] = a.x; v[1] = a.y; v[2] = a.z; v[3] = a.w;
    v[4] = b.x; v[5] = b.y; v[6] = b.z; v[7] = b.w;
  }
  float ss = 0.f;
#pragma unroll
  for (int i = 0; i < 8; ++i) ss += v[i] * v[i];
#pragma unroll
  for (int m = 32; m >= 1; m >>= 1) ss += __shfl_xor(ss, m, 64);
  __shared__ float red[4];
  if ((t & 63) == 0) red[t >> 6] = ss;
  __syncthreads();
  float rs = rsqrtf((red[0] + red[1] + red[2] + red[3]) * (1.0f / 2048.0f) + 1e-5f);
  const float* gp = g + t * 8;
  float4 ga = *(const float4*)gp;
  float4 gb = *(const float4*)(gp + 4);
  float gv[8] = {ga.x, ga.y, ga.z, ga.w, gb.x, gb.y, gb.z, gb.w};
  union { ushort_t u16[8]; uint4 u; } p;
#pragma unroll
  for (int i = 0; i < 8; ++i) p.u16[i] = f2bf(v[i] * rs * gv[i]);
  *(uint4*)&out[(size_t)row * out_ld + t * 8] = p.u;
}

// ---------------------------------------------------------------------------
// Shared GEMM geometry (both kernels): C[M,N] = A[M,K] * Bt[N,K]^T, bf16.
// 128x128 tile, BK=64, XOR-swizzled LDS: linear gload_lds dest, each lane's
// GLOBAL source fetches granule (lane&7)^(row&7); fragment reads apply the
// same XOR -> bank-conflict-free (R11 measured: SQ_LDS_BANK_CONFLICT = 0).
// Requires K % 64 == 0, K >= 128 (all calls: K=2048).
// ---------------------------------------------------------------------------

// gemm_mega: single-buffer (32KB LDS, ~2.6 blocks/CU measured 33% occ).
// For the 1536-block QKV mega-GEMM: inter-block TLP hides staging latency
// (R11/R13: 99.4/99.3us vs 123.9 dbuf). C bf16 = acc. Bt2 = B for n0>=4096.
__global__ __launch_bounds__(256, 2) void gemm_mega(
    const ushort_t* A, int lda, const ushort_t* Bt, const ushort_t* Bt2,
    int ldb, ushort_t* C, int ldc, int M, int N, int K) {
  __shared__ __align__(16) ushort_t As[128][64];
  __shared__ __align__(16) ushort_t Bs[128][64];
  const int t = threadIdx.x;
  const int wid = t >> 6, lane = t & 63;
  const int l15 = lane & 15, quad = lane >> 4;
  const int m0 = blockIdx.y * 128, n0 = blockIdx.x * 128;
  const int wm = (wid >> 1) * 64, wn = (wid & 1) * 64;

  const ushort_t* btb = Bt;
  int nr = n0;
  if (Bt2 != nullptr && n0 >= 4096) { btb = Bt2; nr = n0 - 4096; }

  const int srow = wid * 8 + (lane >> 3);
  const int scol = ((lane & 7) ^ ((lane >> 3) & 7)) * 8;
  const ushort_t* ag = &A[(size_t)(m0 + srow) * lda + scol];
  const ushort_t* bg = &btb[(size_t)(nr + srow) * ldb + scol];
  ushort_t* al = &As[wid * 8][0];   // wave-uniform dest bases
  ushort_t* bl = &Bs[wid * 8][0];

  floatx4 acc[4][4];
#pragma unroll
  for (int i = 0; i < 4; ++i)
#pragma unroll
    for (int j = 0; j < 4; ++j) acc[i][j] = (floatx4){0.f, 0.f, 0.f, 0.f};

  const char* asb = (const char*)&As[0][0];
  const char* bsb = (const char*)&Bs[0][0];
  const int rswz = (l15 & 7);

  for (int k0 = 0; k0 < K; k0 += 64) {
    __syncthreads();
#pragma unroll
    for (int s = 0; s < 4; ++s) {
      load16(ag + (size_t)(s * 32) * lda + k0, al + s * 32 * 64);
      load16(bg + (size_t)(s * 32) * ldb + k0, bl + s * 32 * 64);
    }
    __syncthreads();

#pragma unroll
    for (int kh = 0; kh < 2; ++kh) {
      const int gsel = ((kh * 4 + quad) ^ rswz) * 16;
      short8 af[4], bf[4];
#pragma unroll
      for (int i = 0; i < 4; ++i)
        af[i] = *(const short8*)(asb + (wm + i * 16 + l15) * 128 + gsel);
#pragma unroll
      for (int j = 0; j < 4; ++j)
        bf[j] = *(const short8*)(bsb + (wn + j * 16 + l15) * 128 + gsel);
#pragma unroll
      for (int i = 0; i < 4; ++i)
#pragma unroll
        for (int j = 0; j < 4; ++j)
          acc[i][j] = __builtin_amdgcn_mfma_f32_16x16x32_bf16(af[i], bf[j],
                                                              acc[i][j], 0, 0, 0);
    }
  }

#pragma unroll
  for (int i = 0; i < 4; ++i)
#pragma unroll
    for (int j = 0; j < 4; ++j)
#pragma unroll
      for (int r = 0; r < 4; ++r) {
        int row = m0 + wm + i * 16 + quad * 4 + r;
        int col = n0 + wn + j * 16 + l15;
        C[(size_t)row * ldc + col] = f2bf(acc[i][j][r]);
      }
}

// gemm_tail<MODE>: R12 counted-vmcnt dbuf pipeline (T3+T4+T5), 64KB LDS.
// For the 512-block tails (2/CU-capped: no residency to lose; R12: -33us
// combined vs single-buffer). Stage 2 tiles ahead, drain vmcnt(8) not 0,
// raw s_barrier + sched_barrier(0) fences (rule #18), setprio around MFMA.
// MODE 1: C bf16 = resid(fp32)+acc; MODE 2: C fp32 = resid(bf16)+acc+bias.
template <int MODE>
__global__ __launch_bounds__(256, 2) void gemm_tail(
    const ushort_t* A, int lda, const ushort_t* Bt, int ldb,
    void* Cv, int ldc, const void* resid, int ldr,
    const float* bias, int M, int N, int K) {
  __shared__ __align__(16) ushort_t As[2][128][64];
  __shared__ __align__(16) ushort_t Bs[2][128][64];
  const int t = threadIdx.x;
  const int wid = t >> 6, lane = t & 63;
  const int l15 = lane & 15, quad = lane >> 4;
  const int m0 = blockIdx.y * 128, n0 = blockIdx.x * 128;
  const int wm = (wid >> 1) * 64, wn = (wid & 1) * 64;

  const int srow = wid * 8 + (lane >> 3);
  const int scol = ((lane & 7) ^ ((lane >> 3) & 7)) * 8;
  const ushort_t* ag = &A[(size_t)(m0 + srow) * lda + scol];
  const ushort_t* bg = &Bt[(size_t)(n0 + srow) * ldb + scol];

#define STAGE(BUF, TILE)                                                    \
  do {                                                                      \
    ushort_t* al_ = &As[BUF][wid * 8][0];                                   \
    ushort_t* bl_ = &Bs[BUF][wid * 8][0];                                   \
    const size_t ko_ = (size_t)(TILE)*64;                                   \
    load16(ag + (size_t)0 * lda + ko_,   al_ + 0 * 32 * 64);                \
    load16(ag + (size_t)32 * lda + ko_,  al_ + 1 * 32 * 64);                \
    load16(ag + (size_t)64 * lda + ko_,  al_ + 2 * 32 * 64);                \
    load16(ag + (size_t)96 * lda + ko_,  al_ + 3 * 32 * 64);                \
    load16(bg + (size_t)0 * ldb + ko_,   bl_ + 0 * 32 * 64);                \
    load16(bg + (size_t)32 * ldb + ko_,  bl_ + 1 * 32 * 64);                \
    load16(bg + (size_t)64 * ldb + ko_,  bl_ + 2 * 32 * 64);                \
    load16(bg + (size_t)96 * ldb + ko_,  bl_ + 3 * 32 * 64);                \
  } while (0)

  floatx4 acc[4][4];
#pragma unroll
  for (int i = 0; i < 4; ++i)
#pragma unroll
    for (int j = 0; j < 4; ++j) acc[i][j] = (floatx4){0.f, 0.f, 0.f, 0.f};

  const int rswz = (l15 & 7);
  const int nt = K >> 6;       // K/64 tiles; nt >= 2

  // prologue: tiles 0 and 1 in flight; wait tile 0 (vmcnt(8): 8 newest fly)
  STAGE(0, 0);
  STAGE(1, 1);
  __asm__ __volatile__("s_waitcnt vmcnt(8)");
  __builtin_amdgcn_sched_barrier(0);
  __builtin_amdgcn_s_barrier();
  __builtin_amdgcn_sched_barrier(0);

  for (int tt = 0; tt < nt; ++tt) {
    const int buf = tt & 1;
    const char* asb = (const char*)&As[buf][0][0];
    const char* bsb = (const char*)&Bs[buf][0][0];
    __builtin_amdgcn_s_setprio(1);
#pragma unroll
    for (int kh = 0; kh < 2; ++kh) {
      const int gsel = ((kh * 4 + quad) ^ rswz) * 16;
      short8 af[4], bf[4];
#pragma unroll
      for (int i = 0; i < 4; ++i)
        af[i] = *(const short8*)(asb + (wm + i * 16 + l15) * 128 + gsel);
#pragma unroll
      for (int j = 0; j < 4; ++j)
        bf[j] = *(const short8*)(bsb + (wn + j * 16 + l15) * 128 + gsel);
#pragma unroll
      for (int i = 0; i < 4; ++i)
#pragma unroll
        for (int j = 0; j < 4; ++j)
          acc[i][j] = __builtin_amdgcn_mfma_f32_16x16x32_bf16(af[i], bf[j],
                                                              acc[i][j], 0, 0, 0);
    }
    __builtin_amdgcn_s_setprio(0);

    if (tt + 1 < nt) {
      __builtin_amdgcn_s_barrier();          // all readers of buf done
      __builtin_amdgcn_sched_barrier(0);
      if (tt + 2 < nt) {
        STAGE(buf, tt + 2);                  // refill read buffer, 2 ahead
        __asm__ __volatile__("s_waitcnt vmcnt(8)");  // tile tt+1 landed
      } else {
        __asm__ __volatile__("s_waitcnt vmcnt(0)");  // last tile landed
      }
      __builtin_amdgcn_sched_barrier(0);
      __builtin_amdgcn_s_barrier();          // tile tt+1 visible to all
      __builtin_amdgcn_sched_barrier(0);
    }
  }
#undef STAGE

#pragma unroll
  for (int i = 0; i < 4; ++i)
#pragma unroll
    for (int j = 0; j < 4; ++j)
#pragma unroll
      for (int r = 0; r < 4; ++r) {
        int row = m0 + wm + i * 16 + quad * 4 + r;
        int col = n0 + wn + j * 16 + l15;
        float v = acc[i][j][r];
        if (MODE == 1) {
          float rv = ((const float*)resid)[(size_t)row * ldr + col];
          ((ushort_t*)Cv)[(size_t)row * ldc + col] = f2bf(rv + v);
        } else {
          float rv = bf2f(((const ushort_t*)resid)[(size_t)row * ldr + col]);
          ((float*)Cv)[(size_t)row * ldc + col] = rv + v + bias[col];
        }
      }
}

// ---------------------------------------------------------------------------
// Transpose V section of qkv -> vT[b*16+h][d][s]  (bf16)
// ---------------------------------------------------------------------------
__global__ __launch_bounds__(256) void transpose_v_kernel(
    const ushort_t* __restrict__ qkv, ushort_t* __restrict__ vT) {
  __shared__ __align__(16) ushort_t tile[64][72];  // [d][s]
  const int t = threadIdx.x;
  const int s0 = blockIdx.x * 64, d0 = blockIdx.y * 64;
  const int bh = blockIdx.z, b = bh >> 4, h = bh & 15;
#pragma unroll
  for (int i = 0; i < 2; ++i) {
    int c = t + 256 * i, r = c >> 3, o = (c & 7) * 8;
    uint4 raw = *(const uint4*)&qkv[(size_t)(b * 2048 + s0 + r) * 6144 + 4096 +
                                    h * 128 + d0 + o];
    tile[o + 0][r] = (ushort_t)(raw.x & 0xffffu);
    tile[o + 1][r] = (ushort_t)(raw.x >> 16);
    tile[o + 2][r] = (ushort_t)(raw.y & 0xffffu);
    tile[o + 3][r] = (ushort_t)(raw.y >> 16);
    tile[o + 4][r] = (ushort_t)(raw.z & 0xffffu);
    tile[o + 5][r] = (ushort_t)(raw.z >> 16);
    tile[o + 6][r] = (ushort_t)(raw.w & 0xffffu);
    tile[o + 7][r] = (ushort_t)(raw.w >> 16);
  }
  __syncthreads();
#pragma unroll
  for (int i = 0; i < 2; ++i) {
    int c = t + 256 * i, r = c >> 3, o = (c & 7) * 8;
    *(uint4*)&vT[((size_t)bh * 128 + d0 + r) * 2048 + s0 + o] =
        *(const uint4*)&tile[r][o];
  }
}

// ---------------------------------------------------------------------------
// Flash attention (causal). R10 structure (unchanged):
//  - transposed QK^T -> in-lane softmax (2 shfl_xor per reduce), exp2 domain.
//  - single-barrier double-buffered K/V; staging overlaps compute.
//  - diag-only causal mask; cvt_pk P-pack; T13 defer-max.
//  - complementary q-tile pair per block (33 iters); grid 16x32, 2/CU.
// ---------------------------------------------------------------------------
__global__ __launch_bounds__(256, 2) void attn_kernel(
    const ushort_t* qkv, const ushort_t* vT, ushort_t* ctx, int ldctx) {
  const int S = 2048, LD = 6144, D = 128;
  __shared__ __align__(16) ushort_t Ks[2][64][136];
  __shared__ __align__(16) ushort_t Vt[2][128][72];
  __shared__ __align__(16) ushort_t Ps[4][16][72];
  const int t = threadIdx.x;
  const int wid = t >> 6, lane = t & 63;
  const int l15 = lane & 15, quad = lane >> 4;
  const int bx = (int)blockIdx.x;
  const int bh = blockIdx.y, b = bh >> 4, h = bh & 15;

  const int krow = t >> 4, kcol = (t & 15) * 8;   // K: 64 rows x 16 chunks, x4
  const int vrow = t >> 3, vcol = (t & 7) * 8;    // V: 128 rows x 8 chunks, x4
  const ushort_t* kgp = &qkv[(size_t)(b * S + krow) * LD + 2048 + h * D + kcol];
  const ushort_t* vgp = &vT[((size_t)bh * D + vrow) * S + vcol];

  uint4 k0r, k1r, k2r, k3r, v0r, v1r, v2r, v3r;
#define PREFETCH(KB)                                          \
  do {                                                        \
    const ushort_t* kp_ = kgp + (size_t)(KB)*LD;              \
    k0r = *(const uint4*)(kp_);                               \
    k1r = *(const uint4*)(kp_ + (size_t)16 * LD);             \
    k2r = *(const uint4*)(kp_ + (size_t)32 * LD);             \
    k3r = *(const uint4*)(kp_ + (size_t)48 * LD);             \
    const ushort_t* vp_ = vgp + (KB);                         \
    v0r = *(const uint4*)(vp_);                               \
    v1r = *(const uint4*)(vp_ + (size_t)32 * S);              \
    v2r = *(const uint4*)(vp_ + (size_t)64 * S);              \
    v3r = *(const uint4*)(vp_ + (size_t)96 * S);              \
  } while (0)
#define STAGE(BUF)                                            \
  do {                                                        \
    *(uint4*)&Ks[BUF][krow + 0][kcol]  = k0r;                 \
    *(uint4*)&Ks[BUF][krow + 16][kcol] = k1r;                 \
    *(uint4*)&Ks[BUF][krow + 32][kcol] = k2r;                 \
    *(uint4*)&Ks[BUF][krow + 48][kcol] = k3r;                 \
    *(uint4*)&Vt[BUF][vrow + 0][vcol]  = v0r;                 \
    *(uint4*)&Vt[BUF][vrow + 32][vcol] = v1r;                 \
    *(uint4*)&Vt[BUF][vrow + 64][vcol] = v2r;                 \
    *(uint4*)&Vt[BUF][vrow + 96][vcol] = v3r;                 \
  } while (0)

  const float sc2 = 0.08838834764831845f * 1.4426950408889634f;
  const int nkt0 = 32 - bx;
  const int NT = 33;

  PREFETCH(0);
  STAGE(0);
  PREFETCH(64);

  int g = 0;
  for (int ph = 0; ph < 2; ++ph) {
    const int qtile = ph == 0 ? (31 - bx) : bx;
    const int qb = qtile * 64;

    short8 qf[4];
    {
      const ushort_t* qp =
          &qkv[(size_t)(b * S + qb + wid * 16 + l15) * LD + h * D];
#pragma unroll
      for (int kk = 0; kk < 4; ++kk)
        qf[kk] = *(const short8*)&qp[kk * 32 + quad * 8];
    }

    floatx4 accO[8];
#pragma unroll
    for (int i = 0; i < 8; ++i) accO[i] = (floatx4){0.f, 0.f, 0.f, 0.f};
    float m_i = -1e30f;
    float l_i = 0.f;
    const int qg = qb + wid * 16 + l15;

    const int nkt = qtile + 1;
    for (int kt = 0; kt < nkt; ++kt, ++g) {
      const int kb = kt * 64;
      const int buf = g & 1;
      __syncthreads();
      if (g + 1 < NT) {
        STAGE(buf ^ 1);
        if (g + 2 < NT) {
          const int g2 = g + 2;
          const int kb2 = (g2 < nkt0) ? g2 * 64 : (g2 - nkt0) * 64;
          PREFETCH(kb2);
        }
      }

      floatx4 st[4];
#pragma unroll
      for (int jn = 0; jn < 4; ++jn) {
        st[jn] = (floatx4){0.f, 0.f, 0.f, 0.f};
#pragma unroll
        for (int kk = 0; kk < 4; ++kk) {
          short8 kf = *(const short8*)&Ks[buf][jn * 16 + l15][kk * 32 + quad * 8];
          st[jn] = __builtin_amdgcn_mfma_f32_16x16x32_bf16(kf, qf[kk], st[jn], 0, 0, 0);
        }
      }

      float p[4][4];
      if (kt == nkt - 1) {
#pragma unroll
        for (int jn = 0; jn < 4; ++jn)
#pragma unroll
          for (int r = 0; r < 4; ++r) {
            int kg = kb + jn * 16 + quad * 4 + r;
            float s = st[jn][r] * sc2;
            p[jn][r] = (kg <= qg) ? s : -1e30f;
          }
      } else {
#pragma unroll
        for (int jn = 0; jn < 4; ++jn)
#pragma unroll
          for (int r = 0; r < 4; ++r) p[jn][r] = st[jn][r] * sc2;
      }

      float mq0 = fmaxf(fmaxf(p[0][0], p[0][1]), fmaxf(p[0][2], p[0][3]));
      float mq1 = fmaxf(fmaxf(p[1][0], p[1][1]), fmaxf(p[1][2], p[1][3]));
      float mq2 = fmaxf(fmaxf(p[2][0], p[2][1]), fmaxf(p[2][2], p[2][3]));
      float mq3 = fmaxf(fmaxf(p[3][0], p[3][1]), fmaxf(p[3][2], p[3][3]));
      float v = fmaxf(fmaxf(mq0, mq1), fmaxf(mq2, mq3));
      v = fmaxf(v, __shfl_xor(v, 16, 64));
      v = fmaxf(v, __shfl_xor(v, 32, 64));

      if (!__all(v - m_i <= 8.0f)) {
        float mnew = fmaxf(m_i, v);
        float alpha = exp2f(m_i - mnew);
        m_i = mnew;
        float arow[4];
#pragma unroll
        for (int r = 0; r < 4; ++r) arow[r] = __shfl(alpha, quad * 4 + r, 16);
#pragma unroll
        for (int jd = 0; jd < 8; ++jd)
#pragma unroll
          for (int r = 0; r < 4; ++r) accO[jd][r] *= arow[r];
        l_i *= alpha;
      }

#pragma unroll
      for (int jn = 0; jn < 4; ++jn)
#pragma unroll
        for (int r = 0; r < 4; ++r) p[jn][r] = exp2f(p[jn][r] - m_i);

#pragma unroll
      for (int jn = 0; jn < 4; ++jn) {
        unsigned w0, w1;
        asm("v_cvt_pk_bf16_f32 %0, %1, %2" : "=v"(w0)
            : "v"(p[jn][0]), "v"(p[jn][1]));
        asm("v_cvt_pk_bf16_f32 %0, %1, %2" : "=v"(w1)
            : "v"(p[jn][2]), "v"(p[jn][3]));
        uint2 pk2; pk2.x = w0; pk2.y = w1;
        *(uint2*)&Ps[wid][l15][jn * 16 + quad * 4] = pk2;
      }

      float sq = ((p[0][0] + p[0][1]) + (p[0][2] + p[0][3])) +
                 ((p[1][0] + p[1][1]) + (p[1][2] + p[1][3])) +
                 ((p[2][0] + p[2][1]) + (p[2][2] + p[2][3])) +
                 ((p[3][0] + p[3][1]) + (p[3][2] + p[3][3]));
      sq += __shfl_xor(sq, 16, 64);
      sq += __shfl_xor(sq, 32, 64);
      l_i += sq;

      __asm__ __volatile__("s_waitcnt lgkmcnt(0)" ::: "memory");

      short8 pf[2];
#pragma unroll
      for (int kk = 0; kk < 2; ++kk)
        pf[kk] = *(const short8*)&Ps[wid][l15][kk * 32 + quad * 8];
#pragma unroll
      for (int jd = 0; jd < 8; ++jd)
#pragma unroll
        for (int kk = 0; kk < 2; ++kk) {
          short8 vf = *(const short8*)&Vt[buf][jd * 16 + l15][kk * 32 + quad * 8];
          accO[jd] = __builtin_amdgcn_mfma_f32_16x16x32_bf16(pf[kk], vf, accO[jd], 0, 0, 0);
        }
    }

    float lrow[4];
#pragma unroll
    for (int r = 0; r < 4; ++r) lrow[r] = 1.0f / __shfl(l_i, quad * 4 + r, 16);
#pragma unroll
    for (int jd = 0; jd < 8; ++jd)
#pragma unroll
      for (int r = 0; r < 4; ++r) {
        int row = b * S + qb + wid * 16 + quad * 4 + r;
        int col = h * D + jd * 16 + l15;
        ctx[(size_t)row * ldctx + col] = f2bf(accO[jd][r] * lrow[r]);
      }
  }
#undef PREFETCH
#undef STAGE
}

// ---------------------------------------------------------------------------
extern "C" void kernel_launch(void* const* d_in, const int* in_sizes, int n_in,
                              void* d_out, int out_size, void* d_ws,
                              size_t ws_size, hipStream_t stream) {
  const float* x    = (const float*)d_in[0];
  const float* ln1  = (const float*)d_in[1];
  const float* Wq   = (const float*)d_in[2];
  const float* Wk   = (const float*)d_in[3];
  const float* Wv   = (const float*)d_in[4];
  const float* Wo   = (const float*)d_in[5];
  const float* ln2  = (const float*)d_in[6];
  const float* Wmlp = (const float*)d_in[7];
  const float* bmlp = (const float*)d_in[8];
  float* out = (float*)d_out;

  char* ws = (char*)d_ws;
  ushort_t* qkv = (ushort_t*)(ws + 0);         // [4096][6144] bf16
  ushort_t* R2  = (ushort_t*)(ws + 50331648);  // 16.78 MB region
  ushort_t* WqT   = R2;                        // [2048][2048] bf16
  ushort_t* WkT   = R2 + 4194304;              // contiguous rows 2048..4095
  ushort_t* WoT   = R2;                        // after mega-GEMM (WqT dead)
  ushort_t* WmlpT = R2 + 4194304;              // coexists with WoT
  ushort_t* n1  = (ushort_t*)d_out;            // [4096][2048] bf16 scratch
  ushort_t* WvT = (ushort_t*)d_out + 8388608;  // d_out upper half
  ushort_t* vT  = (ushort_t*)d_out + 8388608;  // vT replaces WvT after mega
  ushort_t* ctx = qkv + 4096;                  // V section, ld 6144
  ushort_t* x1  = qkv + 2048;                  // K section, ld 6144
  ushort_t* n2  = qkv;                         // Q section, ld 6144

  dim3 blk(256);
  dim3 ggrid(16, 32);
  dim3 ggridQKV(48, 32);                       // fused QKV GEMM, N=6144

  // 1) rmsnorm1: x fp32 -> n1 bf16 (d_out lower half)
  rmsnorm_kernel<false><<<dim3(4096), blk, 0, stream>>>(x, 2048, ln1, n1, 2048);

  // 2) batched transpose {Wq,Wk,Wv}; WvT in d_out upper half
  transpose_w_batch<<<dim3(32, 32, 3), blk, 0, stream>>>(Wq, Wk, Wv,
                                                         WqT, WkT, WvT);
  // 3) fused QKV GEMM (single-buffer kernel: 1536 blocks -> TLP hides staging)
  gemm_mega<<<ggridQKV, blk, 0, stream>>>(n1, 2048, WqT, WvT, 2048, qkv, 6144,
                                          4096, 6144, 2048);

  // 4) batched transpose {Wo,Wmlp} into R2 (WqT/WkT dead)
  transpose_w_batch<<<dim3(32, 32, 2), blk, 0, stream>>>(Wo, Wmlp, Wo,
                                                         WoT, WmlpT, WoT);

  // 5) V transpose into d_out upper half (WvT dead)
  transpose_v_kernel<<<dim3(32, 2, 32), blk, 0, stream>>>(qkv, vT);

  // 6) causal flash attention -> ctx (overwrites dead V section)
  attn_kernel<<<dim3(16, 32), blk, 0, stream>>>(qkv, vT, ctx, 6144);

  // 7) out-projection + residual(x) -> x1 bf16 (dbuf pipeline kernel)
  gemm_tail<1><<<ggrid, blk, 0, stream>>>(ctx, 6144, WoT, 2048, x1, 6144,
                                          x, 2048, nullptr, 4096, 2048, 2048);

  // 8) rmsnorm2: x1 -> n2 (dead Q section)
  rmsnorm_kernel<true><<<dim3(4096), blk, 0, stream>>>(x1, 6144, ln2, n2, 6144);

  // 9) MLP + residual(x1 bf16) + bias -> out fp32 (dbuf pipeline kernel)
  gemm_tail<2><<<ggrid, blk, 0, stream>>>(n2, 6144, WmlpT, 2048, out, 2048,
                                          x1, 6144, bmlp, 4096, 2048, 2048);
}